// Round 2
// baseline (144.709 us; speedup 1.0000x reference)
//
#include <hip/hip_runtime.h>

// GAE reverse affine scan + standardize, fully-coalesced version.
// adv_k = delta_k + c_k * adv_{k+1};  delta_k = r_k + g*V_{k+1}*nd_k - V_k;  c_k = g*l*nd_k
// Affine f(x) = D + C*x; compose(left,right) = (Dl + Cl*Dr, Cl*Cr), left = lower index.
// Decomposition: lane owns 4 contiguous elems (one float4) -> wave owns 256 -> block owns 1024.
// Wave scan = 6-step Kogge-Stone shuffle scan over lane affines (no LDS staging of data).

#define GAMMA_F 0.99f
#define GL_F 0.9405f            // 0.99 * 0.95
#define EPS_F 1e-8f

constexpr int NT = 256;          // threads per block
constexpr int PL = 4;            // elements per lane (one float4)
constexpr int WSPAN = 64 * PL;   // 256 elements per wave
constexpr int CHUNK = 4 * WSPAN; // 1024 elements per block

// Load lane's 4 elements (coalesced), produce delta[4], cont[4].
__device__ __forceinline__ void lane_load(const float* __restrict__ r,
                                          const float* __restrict__ v,
                                          const int* __restrict__ dn,
                                          int e0, int lane,
                                          float* d, float* c) {
    float4 rr = *(const float4*)(r + e0);
    float4 vv = *(const float4*)(v + e0);
    int4   dd = *(const int4*)(dn + e0);
    float vnext = __shfl_down(vv.x, 1);
    if (lane == 63) vnext = v[e0 + PL];   // wave-boundary neighbor (valid: v has T+1)
    float va[5] = {vv.x, vv.y, vv.z, vv.w, vnext};
    float rf[4] = {rr.x, rr.y, rr.z, rr.w};
    int   di[4] = {dd.x, dd.y, dd.z, dd.w};
#pragma unroll
    for (int i = 0; i < PL; ++i) {
        float nd = 1.0f - (float)di[i];
        d[i] = rf[i] + GAMMA_F * va[i + 1] * nd - va[i];
        c[i] = GL_F * nd;
    }
}

// Compose lane's 4 affines into group affine (D,C); then wave reverse Kogge-Stone:
// afterwards (D,C) = S_lane = A_lane ∘ A_{lane+1} ∘ ... ∘ A_63.
__device__ __forceinline__ void lane_group_and_scan(const float* d, const float* c,
                                                    int lane, float& D, float& C) {
    D = 0.f; C = 1.f;
#pragma unroll
    for (int i = PL - 1; i >= 0; --i) { D = d[i] + c[i] * D; C *= c[i]; }
#pragma unroll
    for (int off = 1; off < 64; off <<= 1) {
        float tD = __shfl_down(D, off);
        float tC = __shfl_down(C, off);
        if (lane + off < 64) { D = D + C * tD; C = C * tC; }
    }
}

// Pass 1: per-block (1024-elem) composed affine
__global__ __launch_bounds__(NT) void k_chunk_affine(const float* __restrict__ r,
                                                     const float* __restrict__ v,
                                                     const int* __restrict__ dn,
                                                     float2* __restrict__ aff) {
    const int t = threadIdx.x, lane = t & 63, wv = t >> 6;
    const int e0 = blockIdx.x * CHUNK + wv * WSPAN + lane * PL;
    float d[PL], c[PL], D, C;
    lane_load(r, v, dn, e0, lane, d, c);
    lane_group_and_scan(d, c, lane, D, C);
    __shared__ float2 waff[4];
    if (lane == 0) waff[wv] = make_float2(D, C);
    __syncthreads();
    if (t == 0) {
        float BD = 0.f, BC = 1.f;
        for (int w = 3; w >= 0; --w) { BD = waff[w].x + waff[w].y * BD; BC *= waff[w].y; }
        aff[blockIdx.x] = make_float2(BD, BC);
    }
}

// Generic inclusive reverse scan in LDS over NT affines (used by pass 2 only).
__device__ __forceinline__ void block_rscan(float D, float C, float* Ds, float* Cs, int t) {
    Ds[t] = D; Cs[t] = C;
    __syncthreads();
    for (int off = 1; off < NT; off <<= 1) {
        float d2 = 0.f, c2 = 0.f;
        bool act = (t + off) < NT;
        if (act) { d2 = Ds[t + off]; c2 = Cs[t + off]; }
        __syncthreads();
        if (act) { float a = Ds[t] + Cs[t] * d2; float b = Cs[t] * c2; Ds[t] = a; Cs[t] = b; }
        __syncthreads();
    }
}

// Pass 2: reverse scan over nchunk block-affines -> carry-in per block (single block)
__global__ __launch_bounds__(NT) void k_chunk_scan(const float2* __restrict__ aff,
                                                   float* __restrict__ carry, int nchunk) {
    const int t = threadIdx.x;
    const int per = nchunk / NT;   // 64
    const int s = t * per;
    float D = 0.f, C = 1.f;
    for (int i = per - 1; i >= 0; --i) { float2 a = aff[s + i]; D = a.x + a.y * D; C *= a.y; }
    __shared__ float Ds[NT], Cs[NT];
    block_rscan(D, C, Ds, Cs, t);
    float x = (t + 1 < NT) ? Ds[t + 1] : 0.f;
    for (int i = per - 1; i >= 0; --i) {
        int cidx = s + i;
        float2 a = aff[cidx];
        carry[cidx] = x;
        x = a.x + a.y * x;
    }
}

// Pass 3: final adv values + per-block (sum, sumsq)
__global__ __launch_bounds__(NT) void k_final(const float* __restrict__ r,
                                              const float* __restrict__ v,
                                              const int* __restrict__ dn,
                                              const float* __restrict__ carry,
                                              float* __restrict__ out,
                                              double2* __restrict__ partial) {
    const int t = threadIdx.x, lane = t & 63, wv = t >> 6;
    const int blk = blockIdx.x;
    const int e0 = blk * CHUNK + wv * WSPAN + lane * PL;
    float d[PL], c[PL], D, C;
    lane_load(r, v, dn, e0, lane, d, c);
    lane_group_and_scan(d, c, lane, D, C);
    __shared__ float2 waff[4];
    if (lane == 0) waff[wv] = make_float2(D, C);
    __syncthreads();
    float cc = carry[blk];
    // value entering this wave from the right
    float xw = cc;
    for (int w = 3; w > wv; --w) xw = waff[w].x + waff[w].y * xw;
    // value entering this lane's group: apply S_{lane+1}
    float SD = __shfl_down(D, 1), SC = __shfl_down(C, 1);
    if (lane == 63) { SD = 0.f; SC = 1.f; }
    float x = SD + SC * xw;
    float a[PL];
    float ls = 0.f, lq = 0.f;
#pragma unroll
    for (int i = PL - 1; i >= 0; --i) {
        x = d[i] + c[i] * x;
        a[i] = x;
        ls += x; lq += x * x;
    }
    *(float4*)(out + e0) = make_float4(a[0], a[1], a[2], a[3]);

    double s = (double)ls, q = (double)lq;
    for (int off = 32; off > 0; off >>= 1) {
        s += __shfl_down(s, off);
        q += __shfl_down(q, off);
    }
    __shared__ double Ss[4], Sq[4];
    if (lane == 0) { Ss[wv] = s; Sq[wv] = q; }
    __syncthreads();
    if (t == 0) {
        double A = 0.0, B = 0.0;
        for (int w = 0; w < 4; ++w) { A += Ss[w]; B += Sq[w]; }
        partial[blk] = make_double2(A, B);
    }
}

// Pass 4: reduce partials -> mean, 1/(std+eps)
__global__ __launch_bounds__(NT) void k_stats(const double2* __restrict__ partial,
                                              int nchunk, float2* __restrict__ meanstd,
                                              long long T) {
    const int t = threadIdx.x;
    double a = 0.0, b = 0.0;
    for (int i = t; i < nchunk; i += NT) { double2 p = partial[i]; a += p.x; b += p.y; }
    for (int off = 32; off > 0; off >>= 1) {
        a += __shfl_down(a, off);
        b += __shfl_down(b, off);
    }
    __shared__ double Sa[NT / 64], Sb[NT / 64];
    const int wave = t >> 6, lane = t & 63;
    if (lane == 0) { Sa[wave] = a; Sb[wave] = b; }
    __syncthreads();
    if (t == 0) {
        double s = 0.0, q = 0.0;
        for (int w = 0; w < NT / 64; ++w) { s += Sa[w]; q += Sb[w]; }
        double mean = s / (double)T;
        double var = q / (double)T - mean * mean;
        double sd = sqrt(var > 0.0 ? var : 0.0);
        meanstd[0] = make_float2((float)mean, (float)(1.0 / (sd + (double)EPS_F)));
    }
}

// Pass 5: standardize in place
__global__ __launch_bounds__(NT) void k_norm(float* __restrict__ out,
                                             const float2* __restrict__ meanstd,
                                             int n4) {
    const float2 ms = *meanstd;
    float4* o4 = (float4*)out;
    int i = blockIdx.x * blockDim.x + threadIdx.x;
    const int stride = gridDim.x * blockDim.x;
    for (; i < n4; i += stride) {
        float4 v = o4[i];
        v.x = (v.x - ms.x) * ms.y;
        v.y = (v.y - ms.x) * ms.y;
        v.z = (v.z - ms.x) * ms.y;
        v.w = (v.w - ms.x) * ms.y;
        o4[i] = v;
    }
}

extern "C" void kernel_launch(void* const* d_in, const int* in_sizes, int n_in,
                              void* d_out, int out_size, void* d_ws, size_t ws_size,
                              hipStream_t stream) {
    const float* rewards = (const float*)d_in[0];
    const float* v_pred  = (const float*)d_in[1];
    const int*   dones   = (const int*)d_in[2];
    float* out = (float*)d_out;
    const long long T = in_sizes[0];            // 16777216
    const int nchunk = (int)(T / CHUNK);        // 16384

    char* ws = (char*)d_ws;
    float2*  aff     = (float2*)ws;                                   // 16384*8  = 128 KB
    float*   carry   = (float*)(ws + (size_t)nchunk * 8);             // 16384*4  =  64 KB
    double2* partial = (double2*)(ws + (size_t)nchunk * 12);          // 16384*16 = 256 KB (16B aligned)
    float2*  meanstd = (float2*)(ws + (size_t)nchunk * 28);

    hipLaunchKernelGGL(k_chunk_affine, dim3(nchunk), dim3(NT), 0, stream,
                       rewards, v_pred, dones, aff);
    hipLaunchKernelGGL(k_chunk_scan, dim3(1), dim3(NT), 0, stream, aff, carry, nchunk);
    hipLaunchKernelGGL(k_final, dim3(nchunk), dim3(NT), 0, stream,
                       rewards, v_pred, dones, carry, out, partial);
    hipLaunchKernelGGL(k_stats, dim3(1), dim3(NT), 0, stream, partial, nchunk, meanstd, T);
    hipLaunchKernelGGL(k_norm, dim3(4096), dim3(NT), 0, stream, out, meanstd, (int)(T / 4));
}

// Round 3
// 127.868 us; speedup vs baseline: 1.1317x; 1.1317x over previous
//
#include <hip/hip_runtime.h>

// GAE reverse affine scan + standardize — persistent grid-stride version.
// adv_k = delta_k + c_k * adv_{k+1};  delta_k = r_k + g*V_{k+1}*nd_k - V_k;  c_k = g*l*nd_k
// Affine f(x) = D + C*x; compose(left,right) = (Dl + Cl*Dr, Cl*Cr), left = lower index.
// Lane owns 4 contiguous elems (float4); wave owns 256; chunk = 1024 (4 waves);
// 2048 persistent blocks each process 8 chunks (stride 2048 chunks), prefetching
// the next chunk's loads before the current chunk's scan.

#define GAMMA_F 0.99f
#define GL_F 0.9405f            // 0.99 * 0.95
#define EPS_F 1e-8f

constexpr int NT = 256;          // threads per block
constexpr int PL = 4;            // elements per lane
constexpr int WSPAN = 64 * PL;   // 256 elements per wave
constexpr int CHUNK = 4 * WSPAN; // 1024 elements per block-chunk
constexpr int NB = 2048;         // persistent blocks
constexpr int KPB = 8;           // chunks per block  -> nchunk = NB*KPB = 16384

// Compose lane's 4 affines and reverse Kogge-Stone over the wave:
// out (D,C) = A_lane ∘ A_{lane+1} ∘ ... ∘ A_63.
__device__ __forceinline__ void lane_group_and_scan(const float* d, const float* c,
                                                    int lane, float& D, float& C) {
    D = 0.f; C = 1.f;
#pragma unroll
    for (int i = PL - 1; i >= 0; --i) { D = d[i] + c[i] * D; C *= c[i]; }
#pragma unroll
    for (int off = 1; off < 64; off <<= 1) {
        float tD = __shfl_down(D, off);
        float tC = __shfl_down(C, off);
        if (lane + off < 64) { D = D + C * tD; C = C * tC; }
    }
}

// Pass 1: per-chunk composed affine + packed done-mask
__global__ __launch_bounds__(NT, 4) void k_chunk_affine(const float* __restrict__ r,
                                                        const float* __restrict__ v,
                                                        const int* __restrict__ dn,
                                                        float2* __restrict__ aff,
                                                        unsigned long long* __restrict__ dmask) {
    const int t = threadIdx.x, lane = t & 63, wv = t >> 6;
    const int estep = NB * CHUNK;
    int e0 = blockIdx.x * CHUNK + wv * WSPAN + lane * PL;

    float4 rr = *(const float4*)(r + e0);
    float4 vv = *(const float4*)(v + e0);
    int4   dd = *(const int4*)(dn + e0);
    float  vn = (lane == 63) ? v[e0 + PL] : 0.f;

    __shared__ float2 waff[4];

    for (int k = 0; k < KPB; ++k) {
        const int c = blockIdx.x + k * NB;
        float4 rr2 = rr, vv2 = vv; int4 dd2 = dd; float vn2 = 0.f;
        if (k + 1 < KPB) {
            const int e1 = e0 + estep;
            rr2 = *(const float4*)(r + e1);
            vv2 = *(const float4*)(v + e1);
            dd2 = *(const int4*)(dn + e1);
            if (lane == 63) vn2 = v[e1 + PL];
        }

        float vnext = __shfl_down(vv.x, 1);
        if (lane == 63) vnext = vn;
        float va[5] = {vv.x, vv.y, vv.z, vv.w, vnext};
        float rf[4] = {rr.x, rr.y, rr.z, rr.w};
        int   di[4] = {dd.x, dd.y, dd.z, dd.w};
        float d[PL], cc[PL];
#pragma unroll
        for (int i = 0; i < PL; ++i) {
            float nd = 1.0f - (float)di[i];
            d[i]  = rf[i] + GAMMA_F * va[i + 1] * nd - va[i];
            cc[i] = GL_F * nd;
        }
        // pack dones: bit `lane` of word j = (di[j]!=0); 4 words per (chunk,wave)
        unsigned long long m0 = __ballot(di[0] != 0);
        unsigned long long m1 = __ballot(di[1] != 0);
        unsigned long long m2 = __ballot(di[2] != 0);
        unsigned long long m3 = __ballot(di[3] != 0);
        if (lane == 0) {
            unsigned long long* p = dmask + ((size_t)c * 4 + wv) * 4;
            p[0] = m0; p[1] = m1; p[2] = m2; p[3] = m3;
        }

        float D, C;
        lane_group_and_scan(d, cc, lane, D, C);
        if (lane == 0) waff[wv] = make_float2(D, C);
        __syncthreads();
        if (t == 0) {
            float BD = 0.f, BC = 1.f;
            for (int w = 3; w >= 0; --w) { BD = waff[w].x + waff[w].y * BD; BC *= waff[w].y; }
            aff[c] = make_float2(BD, BC);
        }
        __syncthreads();

        rr = rr2; vv = vv2; dd = dd2; vn = vn2; e0 += estep;
    }
}

// Generic inclusive reverse scan in LDS over N affines.
template <int N>
__device__ __forceinline__ void block_rscan(float D, float C, float* Ds, float* Cs, int t) {
    Ds[t] = D; Cs[t] = C;
    __syncthreads();
    for (int off = 1; off < N; off <<= 1) {
        float d2 = 0.f, c2 = 0.f;
        bool act = (t + off) < N;
        if (act) { d2 = Ds[t + off]; c2 = Cs[t + off]; }
        __syncthreads();
        if (act) { float a = Ds[t] + Cs[t] * d2; float b = Cs[t] * c2; Ds[t] = a; Cs[t] = b; }
        __syncthreads();
    }
}

// Pass 2: reverse scan over nchunk chunk-affines -> carry-in per chunk (single 1024-thr block)
__global__ __launch_bounds__(1024) void k_chunk_scan(const float2* __restrict__ aff,
                                                     float* __restrict__ carry, int nchunk) {
    const int t = threadIdx.x;
    const int per = nchunk / 1024;   // 16
    const int s = t * per;
    float D = 0.f, C = 1.f;
    for (int i = per - 1; i >= 0; --i) { float2 a = aff[s + i]; D = a.x + a.y * D; C *= a.y; }
    __shared__ float Ds[1024], Cs[1024];
    block_rscan<1024>(D, C, Ds, Cs, t);
    float x = (t + 1 < 1024) ? Ds[t + 1] : 0.f;
    for (int i = per - 1; i >= 0; --i) {
        int cidx = s + i;
        float2 a = aff[cidx];
        carry[cidx] = x;
        x = a.x + a.y * x;
    }
}

// Pass 3: final adv values + per-persistent-block (sum, sumsq)
__global__ __launch_bounds__(NT, 4) void k_final(const float* __restrict__ r,
                                                 const float* __restrict__ v,
                                                 const unsigned long long* __restrict__ dmask,
                                                 const float* __restrict__ carry,
                                                 float* __restrict__ out,
                                                 double2* __restrict__ partial) {
    const int t = threadIdx.x, lane = t & 63, wv = t >> 6;
    const int estep = NB * CHUNK;
    int e0 = blockIdx.x * CHUNK + wv * WSPAN + lane * PL;

    float4 rr = *(const float4*)(r + e0);
    float4 vv = *(const float4*)(v + e0);
    const unsigned long long* mp = dmask + ((size_t)blockIdx.x * 4 + wv) * 4;
    unsigned long long m[4] = {mp[0], mp[1], mp[2], mp[3]};
    float vn = (lane == 63) ? v[e0 + PL] : 0.f;
    float cy = carry[blockIdx.x];

    __shared__ float2 waff[4];
    double ds = 0.0, dq = 0.0;

    for (int k = 0; k < KPB; ++k) {
        float4 rr2 = rr, vv2 = vv; float vn2 = 0.f, cy2 = 0.f;
        unsigned long long m2[4] = {m[0], m[1], m[2], m[3]};
        if (k + 1 < KPB) {
            const int e1 = e0 + estep;
            const int c1 = blockIdx.x + (k + 1) * NB;
            rr2 = *(const float4*)(r + e1);
            vv2 = *(const float4*)(v + e1);
            const unsigned long long* mq = dmask + ((size_t)c1 * 4 + wv) * 4;
            m2[0] = mq[0]; m2[1] = mq[1]; m2[2] = mq[2]; m2[3] = mq[3];
            if (lane == 63) vn2 = v[e1 + PL];
            cy2 = carry[c1];
        }

        float vnext = __shfl_down(vv.x, 1);
        if (lane == 63) vnext = vn;
        float va[5] = {vv.x, vv.y, vv.z, vv.w, vnext};
        float rf[4] = {rr.x, rr.y, rr.z, rr.w};
        float d[PL], cc[PL];
#pragma unroll
        for (int i = 0; i < PL; ++i) {
            float nd = 1.0f - (float)((m[i] >> lane) & 1ull);
            d[i]  = rf[i] + GAMMA_F * va[i + 1] * nd - va[i];
            cc[i] = GL_F * nd;
        }

        float D, C;
        lane_group_and_scan(d, cc, lane, D, C);
        if (lane == 0) waff[wv] = make_float2(D, C);
        __syncthreads();

        // value entering this wave from the right
        float xw = cy;
        for (int w = 3; w > wv; --w) xw = waff[w].x + waff[w].y * xw;
        // value entering this lane's group
        float SD = __shfl_down(D, 1), SC = __shfl_down(C, 1);
        if (lane == 63) { SD = 0.f; SC = 1.f; }
        float x = SD + SC * xw;
        float a[PL];
        float ls = 0.f, lq = 0.f;
#pragma unroll
        for (int i = PL - 1; i >= 0; --i) {
            x = d[i] + cc[i] * x;
            a[i] = x;
            ls += x; lq += x * x;
        }
        *(float4*)(out + e0) = make_float4(a[0], a[1], a[2], a[3]);
        ds += (double)ls; dq += (double)lq;

        __syncthreads();   // protect waff before next iteration overwrites
        rr = rr2; vv = vv2; vn = vn2; cy = cy2;
        m[0] = m2[0]; m[1] = m2[1]; m[2] = m2[2]; m[3] = m2[3];
        e0 += estep;
    }

    // block reduction of (ds,dq) -> partial[blockIdx.x]
    for (int off = 32; off > 0; off >>= 1) {
        ds += __shfl_down(ds, off);
        dq += __shfl_down(dq, off);
    }
    __shared__ double Ss[4], Sq[4];
    if (lane == 0) { Ss[wv] = ds; Sq[wv] = dq; }
    __syncthreads();
    if (t == 0) {
        double A = 0.0, B = 0.0;
        for (int w = 0; w < 4; ++w) { A += Ss[w]; B += Sq[w]; }
        partial[blockIdx.x] = make_double2(A, B);
    }
}

// Pass 4: reduce 2048 partials -> mean, 1/(std+eps)
__global__ __launch_bounds__(NT) void k_stats(const double2* __restrict__ partial,
                                              int npart, float2* __restrict__ meanstd,
                                              long long T) {
    const int t = threadIdx.x;
    double a = 0.0, b = 0.0;
    for (int i = t; i < npart; i += NT) { double2 p = partial[i]; a += p.x; b += p.y; }
    for (int off = 32; off > 0; off >>= 1) {
        a += __shfl_down(a, off);
        b += __shfl_down(b, off);
    }
    __shared__ double Sa[NT / 64], Sb[NT / 64];
    const int wave = t >> 6, lane = t & 63;
    if (lane == 0) { Sa[wave] = a; Sb[wave] = b; }
    __syncthreads();
    if (t == 0) {
        double s = 0.0, q = 0.0;
        for (int w = 0; w < NT / 64; ++w) { s += Sa[w]; q += Sb[w]; }
        double mean = s / (double)T;
        double var = q / (double)T - mean * mean;
        double sd = sqrt(var > 0.0 ? var : 0.0);
        meanstd[0] = make_float2((float)mean, (float)(1.0 / (sd + (double)EPS_F)));
    }
}

// Pass 5: standardize in place (grid-stride)
__global__ __launch_bounds__(NT, 4) void k_norm(float* __restrict__ out,
                                                const float2* __restrict__ meanstd,
                                                int n4) {
    const float2 ms = *meanstd;
    float4* o4 = (float4*)out;
    int i = blockIdx.x * blockDim.x + threadIdx.x;
    const int stride = gridDim.x * blockDim.x;
    for (; i < n4; i += stride) {
        float4 v = o4[i];
        v.x = (v.x - ms.x) * ms.y;
        v.y = (v.y - ms.x) * ms.y;
        v.z = (v.z - ms.x) * ms.y;
        v.w = (v.w - ms.x) * ms.y;
        o4[i] = v;
    }
}

extern "C" void kernel_launch(void* const* d_in, const int* in_sizes, int n_in,
                              void* d_out, int out_size, void* d_ws, size_t ws_size,
                              hipStream_t stream) {
    const float* rewards = (const float*)d_in[0];
    const float* v_pred  = (const float*)d_in[1];
    const int*   dones   = (const int*)d_in[2];
    float* out = (float*)d_out;
    const long long T = in_sizes[0];            // 16777216
    const int nchunk = (int)(T / CHUNK);        // 16384 = NB*KPB

    char* ws = (char*)d_ws;
    float2*  aff     = (float2*)ws;                                   // 16384*8   = 128 KB
    float*   carry   = (float*)(ws + (size_t)nchunk * 8);             // 16384*4   =  64 KB
    double2* partial = (double2*)(ws + (size_t)nchunk * 12);          // 2048*16   =  32 KB (16B aligned)
    float2*  meanstd = (float2*)(ws + (size_t)nchunk * 12 + 2048 * 16);
    unsigned long long* dmask = (unsigned long long*)(ws + 256 * 1024);  // 16384*16*8 = 2 MB

    hipLaunchKernelGGL(k_chunk_affine, dim3(NB), dim3(NT), 0, stream,
                       rewards, v_pred, dones, aff, dmask);
    hipLaunchKernelGGL(k_chunk_scan, dim3(1), dim3(1024), 0, stream, aff, carry, nchunk);
    hipLaunchKernelGGL(k_final, dim3(NB), dim3(NT), 0, stream,
                       rewards, v_pred, dmask, carry, out, partial);
    hipLaunchKernelGGL(k_stats, dim3(1), dim3(NT), 0, stream, partial, NB, meanstd, T);
    hipLaunchKernelGGL(k_norm, dim3(2048), dim3(NT), 0, stream, out, meanstd, (int)(T / 4));
}

// Round 5
// 115.758 us; speedup vs baseline: 1.2501x; 1.1046x over previous
//
#include <hip/hip_runtime.h>

// GAE reverse affine scan + standardize, 3-kernel wave-private version.
// adv_k = delta_k + c_k*adv_{k+1}; delta_k = r_k + g*V_{k+1}*nd_k - V_k; c_k = g*l*nd_k.
// Affine f(x)=D+C*x; compose(left,right) = (Dl+Cl*Dr, Cl*Cr).
// Each WAVE owns one 1024-elem chunk (2 tiles of 512; lane owns 8 contiguous elems).
// Hot kernels (k_desc, k_apply) have NO __syncthreads and NO LDS — pure shuffles.
// Stats trick: within a chunk adv_i = loc_i + P_i*x  (x = carry entering from right),
// so 5 per-chunk moments {Σloc, ΣP, Σloc², Σloc·P, ΣP²} suffice for global mean/std.

#define GAMMA_F 0.99f
#define GL_F 0.9405f            // 0.99*0.95
#define EPS_F 1e-8f

constexpr int NT = 256;          // 4 waves per block
constexpr int PL = 8;            // elems per lane
constexpr int TILE = 512;        // elems per wave-tile (64*8)
constexpr int CHUNK = 2 * TILE;  // 1024 elems per wave-chunk
constexpr int K2T = 1024;        // k_scan threads

// delta/cont + wave suffix scan for one 512-elem tile.
// Out: d[8], c[8]; sD,sC = inclusive suffix affine at this lane (A_lane∘...∘A_63);
// S1D,S1C = exclusive (from lane+1; identity at lane 63).
__device__ __forceinline__ void tile_scan(const float4& r0, const float4& r1,
                                          const float4& v0, const float4& v1,
                                          const float* nd, float vn63, int lane,
                                          float* d, float* c,
                                          float& sD, float& sC, float& S1D, float& S1C) {
    float vnext = __shfl_down(v0.x, 1);
    if (lane == 63) vnext = vn63;
    float va[9] = {v0.x, v0.y, v0.z, v0.w, v1.x, v1.y, v1.z, v1.w, vnext};
    float rf[8] = {r0.x, r0.y, r0.z, r0.w, r1.x, r1.y, r1.z, r1.w};
#pragma unroll
    for (int i = 0; i < 8; ++i) {
        d[i] = rf[i] + GAMMA_F * va[i + 1] * nd[i] - va[i];
        c[i] = GL_F * nd[i];
    }
    float D = 0.f, C = 1.f;
#pragma unroll
    for (int i = 7; i >= 0; --i) { D = d[i] + c[i] * D; C *= c[i]; }
#pragma unroll
    for (int off = 1; off < 64; off <<= 1) {
        float tD = __shfl_down(D, off);
        float tC = __shfl_down(C, off);
        if (lane + off < 64) { D = D + C * tD; C = C * tC; }
    }
    sD = D; sC = C;
    S1D = __shfl_down(D, 1); S1C = __shfl_down(C, 1);
    if (lane == 63) { S1D = 0.f; S1C = 1.f; }
}

// Per-lane tile-local moments (entry value 0 at tile right edge):
// mm = {Σloc, ΣP, Σloc², Σloc·P, ΣP²} over this lane's 8 elems.
__device__ __forceinline__ void lane_moms(const float* d, const float* c,
                                          float S1D, float S1C, float* mm) {
    float x = S1D, P = S1C;
    float A = 0.f, Pp = 0.f, L2 = 0.f, LP = 0.f, P2 = 0.f;
#pragma unroll
    for (int i = 7; i >= 0; --i) {
        x = d[i] + c[i] * x;   // loc_i
        P *= c[i];             // P_i
        A += x; Pp += P; L2 += x * x; LP += x * P; P2 += P * P;
    }
    mm[0] = A; mm[1] = Pp; mm[2] = L2; mm[3] = LP; mm[4] = P2;
}

// Pass 1: per-chunk desc + moments + packed done-mask. No barriers, no LDS.
__global__ __launch_bounds__(NT) void k_desc(const float* __restrict__ r,
                                             const float* __restrict__ v,
                                             const int* __restrict__ dn,
                                             float2* __restrict__ desc,
                                             float4* __restrict__ mom4,
                                             float* __restrict__ mom1,
                                             unsigned long long* __restrict__ dmask) {
    const int tid = threadIdx.x, lane = tid & 63, wv = tid >> 6;
    const int ch = blockIdx.x * 4 + wv;
    const int base = ch * CHUNK;
    const int o0 = base + lane * PL, o1 = base + TILE + lane * PL;

    float4 r00 = *(const float4*)(r + o0), r01 = *(const float4*)(r + o0 + 4);
    float4 v00 = *(const float4*)(v + o0), v01 = *(const float4*)(v + o0 + 4);
    int4   a00 = *(const int4*)(dn + o0),  a01 = *(const int4*)(dn + o0 + 4);
    float4 r10 = *(const float4*)(r + o1), r11 = *(const float4*)(r + o1 + 4);
    float4 v10 = *(const float4*)(v + o1), v11 = *(const float4*)(v + o1 + 4);
    int4   a10 = *(const int4*)(dn + o1),  a11 = *(const int4*)(dn + o1 + 4);

    float vn63_t1 = (lane == 63) ? v[base + CHUNK] : 0.f;   // v has T+1 elems
    float vn63_t0 = __shfl(v10.x, 0);

    int di0[8] = {a00.x, a00.y, a00.z, a00.w, a01.x, a01.y, a01.z, a01.w};
    int di1[8] = {a10.x, a10.y, a10.z, a10.w, a11.x, a11.y, a11.z, a11.w};
    float nd0[8], nd1[8];
    unsigned long long m0[8], m1[8];
#pragma unroll
    for (int i = 0; i < 8; ++i) {
        nd0[i] = 1.f - (float)di0[i]; m0[i] = __ballot(di0[i] != 0);
        nd1[i] = 1.f - (float)di1[i]; m1[i] = __ballot(di1[i] != 0);
    }

    float d1[8], c1[8], sD1, sC1, S1D1, S1C1;
    tile_scan(r10, r11, v10, v11, nd1, vn63_t1, lane, d1, c1, sD1, sC1, S1D1, S1C1);
    const float T1D = __shfl(sD1, 0), T1C = __shfl(sC1, 0);
    float d0[8], c0[8], sD0, sC0, S1D0, S1C0;
    tile_scan(r00, r01, v00, v01, nd0, vn63_t0, lane, d0, c0, sD0, sC0, S1D0, S1C0);
    const float T0D = __shfl(sD0, 0), T0C = __shfl(sC0, 0);

    float mm1[5], mm0[5];
    lane_moms(d1, c1, S1D1, S1C1, mm1);
    lane_moms(d0, c0, S1D0, S1C0, mm0);
    // lift tile0 moments through tile1's affine (e,f): loc' = loc + P*e, P' = P*f
    const float e = T1D, f = T1C;
    float gA  = mm1[0] + mm0[0] + e * mm0[1];
    float gP  = mm1[1] + f * mm0[1];
    float gL2 = mm1[2] + mm0[2] + 2.f * e * mm0[3] + e * e * mm0[4];
    float gLP = mm1[3] + f * (mm0[3] + e * mm0[4]);
    float gP2 = mm1[4] + f * f * mm0[4];
#pragma unroll
    for (int off = 32; off > 0; off >>= 1) {
        gA  += __shfl_down(gA,  off);
        gP  += __shfl_down(gP,  off);
        gL2 += __shfl_down(gL2, off);
        gLP += __shfl_down(gLP, off);
        gP2 += __shfl_down(gP2, off);
    }
    if (lane == 0) {
        desc[ch] = make_float2(T0D + T0C * T1D, T0C * T1C);
        mom4[ch] = make_float4(gA, gP, gL2, gLP);
        mom1[ch] = gP2;
        unsigned long long* mp = dmask + (size_t)ch * 16;
#pragma unroll
        for (int i = 0; i < 8; ++i) { mp[i] = m0[i]; mp[8 + i] = m1[i]; }
    }
}

// Pass 2: scan chunk descs -> carries; combine moments -> mean, 1/(std+eps).
__global__ __launch_bounds__(K2T) void k_scan(const float2* __restrict__ desc,
                                              const float4* __restrict__ mom4,
                                              const float* __restrict__ mom1,
                                              float* __restrict__ carry,
                                              float2* __restrict__ meanstd,
                                              int nchunk, long long T) {
    const int t = threadIdx.x;
    const int per = nchunk / K2T;   // 16
    const int s = t * per;
    float D = 0.f, C = 1.f;
    for (int i = per - 1; i >= 0; --i) { float2 a = desc[s + i]; D = a.x + a.y * D; C *= a.y; }
    __shared__ float Ds[K2T], Cs[K2T];
    Ds[t] = D; Cs[t] = C;
    __syncthreads();
    for (int off = 1; off < K2T; off <<= 1) {
        float d2 = 0.f, c2 = 0.f;
        bool act = (t + off) < K2T;
        if (act) { d2 = Ds[t + off]; c2 = Cs[t + off]; }
        __syncthreads();
        if (act) { float a = Ds[t] + Cs[t] * d2; float b = Cs[t] * c2; Ds[t] = a; Cs[t] = b; }
        __syncthreads();
    }
    float x = (t + 1 < K2T) ? Ds[t + 1] : 0.f;
    double gS = 0.0, gQ = 0.0;
    for (int i = per - 1; i >= 0; --i) {
        const int cix = s + i;
        carry[cix] = x;
        float4 m = mom4[cix];
        float p2 = mom1[cix];
        gS += (double)(m.x + x * m.y);
        gQ += (double)(m.z + 2.f * x * m.w + x * x * p2);
        float2 a = desc[cix];
        x = a.x + a.y * x;
    }
    for (int off = 32; off > 0; off >>= 1) {
        gS += __shfl_down(gS, off);
        gQ += __shfl_down(gQ, off);
    }
    __shared__ double Sa[K2T / 64], Sb[K2T / 64];
    const int wv = t >> 6, lane = t & 63;
    if (lane == 0) { Sa[wv] = gS; Sb[wv] = gQ; }
    __syncthreads();
    if (t == 0) {
        double S = 0.0, Q = 0.0;
        for (int w = 0; w < K2T / 64; ++w) { S += Sa[w]; Q += Sb[w]; }
        double mean = S / (double)T;
        double var = Q / (double)T - mean * mean;
        double sd = sqrt(var > 0.0 ? var : 0.0);
        meanstd[0] = make_float2((float)mean, (float)(1.0 / (sd + (double)EPS_F)));
    }
}

// Pass 3: recompute, apply carry, normalize inline, write out. No barriers, no LDS.
__global__ __launch_bounds__(NT) void k_apply(const float* __restrict__ r,
                                              const float* __restrict__ v,
                                              const unsigned long long* __restrict__ dmask,
                                              const float* __restrict__ carry,
                                              const float2* __restrict__ meanstd,
                                              float* __restrict__ out) {
    const int tid = threadIdx.x, lane = tid & 63, wv = tid >> 6;
    const int ch = blockIdx.x * 4 + wv;
    const int base = ch * CHUNK;
    const int o0 = base + lane * PL, o1 = base + TILE + lane * PL;

    float4 r00 = *(const float4*)(r + o0), r01 = *(const float4*)(r + o0 + 4);
    float4 v00 = *(const float4*)(v + o0), v01 = *(const float4*)(v + o0 + 4);
    float4 r10 = *(const float4*)(r + o1), r11 = *(const float4*)(r + o1 + 4);
    float4 v10 = *(const float4*)(v + o1), v11 = *(const float4*)(v + o1 + 4);
    const unsigned long long* mp = dmask + (size_t)ch * 16;

    float vn63_t1 = (lane == 63) ? v[base + CHUNK] : 0.f;
    float vn63_t0 = __shfl(v10.x, 0);
    const float2 ms = meanstd[0];
    const float cy = carry[ch];

    float nd0[8], nd1[8];
#pragma unroll
    for (int i = 0; i < 8; ++i) {
        nd0[i] = 1.f - (float)((mp[i] >> lane) & 1ull);
        nd1[i] = 1.f - (float)((mp[8 + i] >> lane) & 1ull);
    }

    float d1[8], c1[8], sD1, sC1, S1D1, S1C1;
    tile_scan(r10, r11, v10, v11, nd1, vn63_t1, lane, d1, c1, sD1, sC1, S1D1, S1C1);
    const float T1D = __shfl(sD1, 0), T1C = __shfl(sC1, 0);
    float d0[8], c0[8], sD0, sC0, S1D0, S1C0;
    tile_scan(r00, r01, v00, v01, nd0, vn63_t0, lane, d0, c0, sD0, sC0, S1D0, S1C0);

    float o[8];
    // tile1: entry value = cy at chunk right edge
    float x = S1D1 + S1C1 * cy;
#pragma unroll
    for (int i = 7; i >= 0; --i) { x = d1[i] + c1[i] * x; o[i] = (x - ms.x) * ms.y; }
    *(float4*)(out + o1)     = make_float4(o[0], o[1], o[2], o[3]);
    *(float4*)(out + o1 + 4) = make_float4(o[4], o[5], o[6], o[7]);
    // tile0: entry value = A_tile1(cy)
    const float x0e = T1D + T1C * cy;
    x = S1D0 + S1C0 * x0e;
#pragma unroll
    for (int i = 7; i >= 0; --i) { x = d0[i] + c0[i] * x; o[i] = (x - ms.x) * ms.y; }
    *(float4*)(out + o0)     = make_float4(o[0], o[1], o[2], o[3]);
    *(float4*)(out + o0 + 4) = make_float4(o[4], o[5], o[6], o[7]);
}

extern "C" void kernel_launch(void* const* d_in, const int* in_sizes, int n_in,
                              void* d_out, int out_size, void* d_ws, size_t ws_size,
                              hipStream_t stream) {
    const float* rewards = (const float*)d_in[0];
    const float* v_pred  = (const float*)d_in[1];
    const int*   dones   = (const int*)d_in[2];
    float* out = (float*)d_out;
    const long long T = in_sizes[0];          // 16777216
    const int nchunk = (int)(T / CHUNK);      // 16384

    // workspace layout (all 16B-aligned)
    char* ws = (char*)d_ws;
    float4* mom4 = (float4*)ws;                                  // 256 KB
    size_t off = (size_t)nchunk * 16;
    float2* desc = (float2*)(ws + off);  off += (size_t)nchunk * 8;   // 128 KB
    float*  mom1 = (float*)(ws + off);   off += (size_t)nchunk * 4;   // 64 KB
    float*  carry = (float*)(ws + off);  off += (size_t)nchunk * 4;   // 64 KB
    float2* meanstd = (float2*)(ws + off); off += 16;
    unsigned long long* dmask = (unsigned long long*)(ws + off);      // 2 MB

    hipLaunchKernelGGL(k_desc, dim3(nchunk / 4), dim3(NT), 0, stream,
                       rewards, v_pred, dones, desc, mom4, mom1, dmask);
    hipLaunchKernelGGL(k_scan, dim3(1), dim3(K2T), 0, stream,
                       desc, mom4, mom1, carry, meanstd, nchunk, T);
    hipLaunchKernelGGL(k_apply, dim3(nchunk / 4), dim3(NT), 0, stream,
                       rewards, v_pred, dmask, carry, meanstd, out);
}

// Round 6
// 106.837 us; speedup vs baseline: 1.3545x; 1.0835x over previous
//
#include <hip/hip_runtime.h>
#include <hip/hip_fp16.h>

// GAE reverse affine scan + standardize.
// adv_k = delta_k + c_k*adv_{k+1}; delta_k = r_k + g*V_{k+1}*nd_k - V_k; c_k = g*l*nd_k.
// Affine f(x)=D+C*x; compose(left,right) = (Dl+Cl*Dr, Cl*Cr).
// Wave owns a 1024-elem chunk (2 tiles of 512; lane owns 8 contiguous elems).
// NEW vs R5: pass 1 persists delta (fp16 in ws if it fits, else f32 staged in d_out),
// so pass 3 reads ~34 MB instead of re-reading r,v (128 MB).

#define GAMMA_F 0.99f
#define GL_F 0.9405f            // 0.99*0.95
#define EPS_F 1e-8f

constexpr int NT = 256;          // 4 waves per block
constexpr int PL = 8;            // elems per lane
constexpr int TILE = 512;        // elems per wave-tile (64*8)
constexpr int CHUNK = 2 * TILE;  // 1024 elems per wave-chunk
constexpr int K2T = 1024;        // k_scan threads

union H8 { __half h[8]; float4 f4; };

// Suffix scan of 8 per-lane affines across the wave.
// sD,sC = A_lane∘...∘A_63 ; S1D,S1C = exclusive (identity at lane 63).
__device__ __forceinline__ void scan8(const float* d, const float* c, int lane,
                                      float& sD, float& sC, float& S1D, float& S1C) {
    float D = 0.f, C = 1.f;
#pragma unroll
    for (int i = 7; i >= 0; --i) { D = d[i] + c[i] * D; C *= c[i]; }
#pragma unroll
    for (int off = 1; off < 64; off <<= 1) {
        float tD = __shfl_down(D, off);
        float tC = __shfl_down(C, off);
        if (lane + off < 64) { D = D + C * tD; C = C * tC; }
    }
    sD = D; sC = C;
    S1D = __shfl_down(D, 1); S1C = __shfl_down(C, 1);
    if (lane == 63) { S1D = 0.f; S1C = 1.f; }
}

// delta/cont for one 512-elem tile from raw inputs, then scan.
__device__ __forceinline__ void tile_scan(const float4& r0, const float4& r1,
                                          const float4& v0, const float4& v1,
                                          const float* nd, float vn63, int lane,
                                          float* d, float* c,
                                          float& sD, float& sC, float& S1D, float& S1C) {
    float vnext = __shfl_down(v0.x, 1);
    if (lane == 63) vnext = vn63;
    float va[9] = {v0.x, v0.y, v0.z, v0.w, v1.x, v1.y, v1.z, v1.w, vnext};
    float rf[8] = {r0.x, r0.y, r0.z, r0.w, r1.x, r1.y, r1.z, r1.w};
#pragma unroll
    for (int i = 0; i < 8; ++i) {
        d[i] = rf[i] + GAMMA_F * va[i + 1] * nd[i] - va[i];
        c[i] = GL_F * nd[i];
    }
    scan8(d, c, lane, sD, sC, S1D, S1C);
}

// Per-lane tile-local moments (entry 0 at tile right edge): {Σloc, ΣP, Σloc², Σloc·P, ΣP²}.
__device__ __forceinline__ void lane_moms(const float* d, const float* c,
                                          float S1D, float S1C, float* mm) {
    float x = S1D, P = S1C;
    float A = 0.f, Pp = 0.f, L2 = 0.f, LP = 0.f, P2 = 0.f;
#pragma unroll
    for (int i = 7; i >= 0; --i) {
        x = d[i] + c[i] * x;
        P *= c[i];
        A += x; Pp += P; L2 += x * x; LP += x * P; P2 += P * P;
    }
    mm[0] = A; mm[1] = Pp; mm[2] = L2; mm[3] = LP; mm[4] = P2;
}

// Pass 1: per-chunk desc + moments + done-mask + persisted delta. No barriers, no LDS.
template <bool HALF>
__global__ __launch_bounds__(NT) void k_desc(const float* __restrict__ r,
                                             const float* __restrict__ v,
                                             const int* __restrict__ dn,
                                             float2* __restrict__ desc,
                                             float4* __restrict__ mom4,
                                             float* __restrict__ mom1,
                                             unsigned long long* __restrict__ dmask,
                                             __half* __restrict__ dh,
                                             float* __restrict__ dfull) {
    const int tid = threadIdx.x, lane = tid & 63, wv = tid >> 6;
    const int ch = blockIdx.x * 4 + wv;
    const int base = ch * CHUNK;
    const int o0 = base + lane * PL, o1 = base + TILE + lane * PL;

    float4 r00 = *(const float4*)(r + o0), r01 = *(const float4*)(r + o0 + 4);
    float4 v00 = *(const float4*)(v + o0), v01 = *(const float4*)(v + o0 + 4);
    int4   a00 = *(const int4*)(dn + o0),  a01 = *(const int4*)(dn + o0 + 4);
    float4 r10 = *(const float4*)(r + o1), r11 = *(const float4*)(r + o1 + 4);
    float4 v10 = *(const float4*)(v + o1), v11 = *(const float4*)(v + o1 + 4);
    int4   a10 = *(const int4*)(dn + o1),  a11 = *(const int4*)(dn + o1 + 4);

    float vn63_t1 = (lane == 63) ? v[base + CHUNK] : 0.f;   // v has T+1 elems
    float vn63_t0 = __shfl(v10.x, 0);

    int di0[8] = {a00.x, a00.y, a00.z, a00.w, a01.x, a01.y, a01.z, a01.w};
    int di1[8] = {a10.x, a10.y, a10.z, a10.w, a11.x, a11.y, a11.z, a11.w};
    float nd0[8], nd1[8];
    unsigned long long m0[8], m1[8];
#pragma unroll
    for (int i = 0; i < 8; ++i) {
        nd0[i] = 1.f - (float)di0[i]; m0[i] = __ballot(di0[i] != 0);
        nd1[i] = 1.f - (float)di1[i]; m1[i] = __ballot(di1[i] != 0);
    }

    float d1[8], c1[8], sD1, sC1, S1D1, S1C1;
    tile_scan(r10, r11, v10, v11, nd1, vn63_t1, lane, d1, c1, sD1, sC1, S1D1, S1C1);
    const float T1D = __shfl(sD1, 0), T1C = __shfl(sC1, 0);
    float d0[8], c0[8], sD0, sC0, S1D0, S1C0;
    tile_scan(r00, r01, v00, v01, nd0, vn63_t0, lane, d0, c0, sD0, sC0, S1D0, S1C0);
    const float T0D = __shfl(sD0, 0), T0C = __shfl(sC0, 0);

    // persist delta
    if (HALF) {
        H8 u0, u1;
#pragma unroll
        for (int i = 0; i < 8; ++i) { u0.h[i] = __float2half(d0[i]); u1.h[i] = __float2half(d1[i]); }
        *(float4*)(dh + o0) = u0.f4;
        *(float4*)(dh + o1) = u1.f4;
    } else {
        *(float4*)(dfull + o0)     = make_float4(d0[0], d0[1], d0[2], d0[3]);
        *(float4*)(dfull + o0 + 4) = make_float4(d0[4], d0[5], d0[6], d0[7]);
        *(float4*)(dfull + o1)     = make_float4(d1[0], d1[1], d1[2], d1[3]);
        *(float4*)(dfull + o1 + 4) = make_float4(d1[4], d1[5], d1[6], d1[7]);
    }

    float mm1[5], mm0[5];
    lane_moms(d1, c1, S1D1, S1C1, mm1);
    lane_moms(d0, c0, S1D0, S1C0, mm0);
    const float e = T1D, f = T1C;   // lift tile0 moments through tile1's affine
    float gA  = mm1[0] + mm0[0] + e * mm0[1];
    float gP  = mm1[1] + f * mm0[1];
    float gL2 = mm1[2] + mm0[2] + 2.f * e * mm0[3] + e * e * mm0[4];
    float gLP = mm1[3] + f * (mm0[3] + e * mm0[4]);
    float gP2 = mm1[4] + f * f * mm0[4];
#pragma unroll
    for (int off = 32; off > 0; off >>= 1) {
        gA  += __shfl_down(gA,  off);
        gP  += __shfl_down(gP,  off);
        gL2 += __shfl_down(gL2, off);
        gLP += __shfl_down(gLP, off);
        gP2 += __shfl_down(gP2, off);
    }
    if (lane == 0) {
        desc[ch] = make_float2(T0D + T0C * T1D, T0C * T1C);
        mom4[ch] = make_float4(gA, gP, gL2, gLP);
        mom1[ch] = gP2;
        unsigned long long* mp = dmask + (size_t)ch * 16;
#pragma unroll
        for (int i = 0; i < 8; ++i) { mp[i] = m0[i]; mp[8 + i] = m1[i]; }
    }
}

// Pass 2: scan chunk descs -> carries; combine moments -> mean, 1/(std+eps).
__global__ __launch_bounds__(K2T) void k_scan(const float2* __restrict__ desc,
                                              const float4* __restrict__ mom4,
                                              const float* __restrict__ mom1,
                                              float* __restrict__ carry,
                                              float2* __restrict__ meanstd,
                                              int nchunk, long long T) {
    const int t = threadIdx.x;
    const int per = nchunk / K2T;   // 16
    const int s = t * per;
    float D = 0.f, C = 1.f;
    for (int i = per - 1; i >= 0; --i) { float2 a = desc[s + i]; D = a.x + a.y * D; C *= a.y; }
    __shared__ float Ds[K2T], Cs[K2T];
    Ds[t] = D; Cs[t] = C;
    __syncthreads();
    for (int off = 1; off < K2T; off <<= 1) {
        float d2 = 0.f, c2 = 0.f;
        bool act = (t + off) < K2T;
        if (act) { d2 = Ds[t + off]; c2 = Cs[t + off]; }
        __syncthreads();
        if (act) { float a = Ds[t] + Cs[t] * d2; float b = Cs[t] * c2; Ds[t] = a; Cs[t] = b; }
        __syncthreads();
    }
    float x = (t + 1 < K2T) ? Ds[t + 1] : 0.f;
    double gS = 0.0, gQ = 0.0;
    for (int i = per - 1; i >= 0; --i) {
        const int cix = s + i;
        carry[cix] = x;
        float4 m = mom4[cix];
        float p2 = mom1[cix];
        gS += (double)(m.x + x * m.y);
        gQ += (double)(m.z + 2.f * x * m.w + x * x * p2);
        float2 a = desc[cix];
        x = a.x + a.y * x;
    }
    for (int off = 32; off > 0; off >>= 1) {
        gS += __shfl_down(gS, off);
        gQ += __shfl_down(gQ, off);
    }
    __shared__ double Sa[K2T / 64], Sb[K2T / 64];
    const int wv = t >> 6, lane = t & 63;
    if (lane == 0) { Sa[wv] = gS; Sb[wv] = gQ; }
    __syncthreads();
    if (t == 0) {
        double S = 0.0, Q = 0.0;
        for (int w = 0; w < K2T / 64; ++w) { S += Sa[w]; Q += Sb[w]; }
        double mean = S / (double)T;
        double var = Q / (double)T - mean * mean;
        double sd = sqrt(var > 0.0 ? var : 0.0);
        meanstd[0] = make_float2((float)mean, (float)(1.0 / (sd + (double)EPS_F)));
    }
}

// Pass 3: read persisted delta + mask, scan, apply carry, normalize, write out.
template <bool HALF>
__global__ __launch_bounds__(NT) void k_apply(const __half* __restrict__ dh,
                                              float* dfull,   // == out in f32 path (in-place)
                                              const unsigned long long* __restrict__ dmask,
                                              const float* __restrict__ carry,
                                              const float2* __restrict__ meanstd,
                                              float* out) {
    const int tid = threadIdx.x, lane = tid & 63, wv = tid >> 6;
    const int ch = blockIdx.x * 4 + wv;
    const int base = ch * CHUNK;
    const int o0 = base + lane * PL, o1 = base + TILE + lane * PL;

    float d0[8], d1[8];
    if (HALF) {
        H8 u0, u1;
        u0.f4 = *(const float4*)(dh + o0);
        u1.f4 = *(const float4*)(dh + o1);
#pragma unroll
        for (int i = 0; i < 8; ++i) { d0[i] = __half2float(u0.h[i]); d1[i] = __half2float(u1.h[i]); }
    } else {
        float4 a0 = *(const float4*)(dfull + o0), b0 = *(const float4*)(dfull + o0 + 4);
        float4 a1 = *(const float4*)(dfull + o1), b1 = *(const float4*)(dfull + o1 + 4);
        d0[0]=a0.x; d0[1]=a0.y; d0[2]=a0.z; d0[3]=a0.w; d0[4]=b0.x; d0[5]=b0.y; d0[6]=b0.z; d0[7]=b0.w;
        d1[0]=a1.x; d1[1]=a1.y; d1[2]=a1.z; d1[3]=a1.w; d1[4]=b1.x; d1[5]=b1.y; d1[6]=b1.z; d1[7]=b1.w;
    }
    const unsigned long long* mp = dmask + (size_t)ch * 16;
    float c0[8], c1[8];
#pragma unroll
    for (int i = 0; i < 8; ++i) {
        c0[i] = GL_F * (1.f - (float)((mp[i] >> lane) & 1ull));
        c1[i] = GL_F * (1.f - (float)((mp[8 + i] >> lane) & 1ull));
    }
    const float2 ms = meanstd[0];
    const float cy = carry[ch];

    float sD1, sC1, S1D1, S1C1;
    scan8(d1, c1, lane, sD1, sC1, S1D1, S1C1);
    const float T1D = __shfl(sD1, 0), T1C = __shfl(sC1, 0);
    float sD0, sC0, S1D0, S1C0;
    scan8(d0, c0, lane, sD0, sC0, S1D0, S1C0);

    float o[8];
    float x = S1D1 + S1C1 * cy;                   // tile1: entry = cy at chunk right edge
#pragma unroll
    for (int i = 7; i >= 0; --i) { x = d1[i] + c1[i] * x; o[i] = (x - ms.x) * ms.y; }
    *(float4*)(out + o1)     = make_float4(o[0], o[1], o[2], o[3]);
    *(float4*)(out + o1 + 4) = make_float4(o[4], o[5], o[6], o[7]);
    const float x0e = T1D + T1C * cy;             // tile0: entry = A_tile1(cy)
    x = S1D0 + S1C0 * x0e;
#pragma unroll
    for (int i = 7; i >= 0; --i) { x = d0[i] + c0[i] * x; o[i] = (x - ms.x) * ms.y; }
    *(float4*)(out + o0)     = make_float4(o[0], o[1], o[2], o[3]);
    *(float4*)(out + o0 + 4) = make_float4(o[4], o[5], o[6], o[7]);
}

extern "C" void kernel_launch(void* const* d_in, const int* in_sizes, int n_in,
                              void* d_out, int out_size, void* d_ws, size_t ws_size,
                              hipStream_t stream) {
    const float* rewards = (const float*)d_in[0];
    const float* v_pred  = (const float*)d_in[1];
    const int*   dones   = (const int*)d_in[2];
    float* out = (float*)d_out;
    const long long T = in_sizes[0];          // 16777216
    const int nchunk = (int)(T / CHUNK);      // 16384

    // workspace layout
    char* ws = (char*)d_ws;
    float4* mom4 = (float4*)ws;                                       // 256 KB
    float2* desc = (float2*)(ws + (size_t)nchunk * 16);               // 128 KB
    float*  mom1 = (float*)(ws + (size_t)nchunk * 24);                // 64 KB
    float*  carry = (float*)(ws + (size_t)nchunk * 28);               // 64 KB
    float2* meanstd = (float2*)(ws + (size_t)nchunk * 32);            // 16 B
    unsigned long long* dmask = (unsigned long long*)(ws + (size_t)nchunk * 32 + 16);  // 2 MB
    const size_t dh_off = 4ull * 1024 * 1024;                         // 4 MB, past everything
    __half* dh = (__half*)(ws + dh_off);                              // 32 MB
    const size_t need = dh_off + (size_t)T * sizeof(__half);
    const bool half_path = (ws_size >= need);

    if (half_path) {
        hipLaunchKernelGGL((k_desc<true>), dim3(nchunk / 4), dim3(NT), 0, stream,
                           rewards, v_pred, dones, desc, mom4, mom1, dmask, dh, (float*)nullptr);
        hipLaunchKernelGGL(k_scan, dim3(1), dim3(K2T), 0, stream,
                           desc, mom4, mom1, carry, meanstd, nchunk, T);
        hipLaunchKernelGGL((k_apply<true>), dim3(nchunk / 4), dim3(NT), 0, stream,
                           dh, (float*)nullptr, dmask, carry, meanstd, out);
    } else {
        // stage f32 delta in d_out, rewrite in place
        hipLaunchKernelGGL((k_desc<false>), dim3(nchunk / 4), dim3(NT), 0, stream,
                           rewards, v_pred, dones, desc, mom4, mom1, dmask, (__half*)nullptr, out);
        hipLaunchKernelGGL(k_scan, dim3(1), dim3(K2T), 0, stream,
                           desc, mom4, mom1, carry, meanstd, nchunk, T);
        hipLaunchKernelGGL((k_apply<false>), dim3(nchunk / 4), dim3(NT), 0, stream,
                           (const __half*)nullptr, out, dmask, carry, meanstd, out);
    }
}